// Round 1
// baseline (380.684 us; speedup 1.0000x reference)
//
#include <hip/hip_runtime.h>
#include <hip/hip_bf16.h>

// MultiScaleFeatureExtractor on MI355X (gfx950)
// Math restructuring:
//   logits = x @ (Wx@Wslice) + (bx@Wslice + bslice)      (px never materialized)
//   out[s,d] = (sum_n w[n,s]*fx[n,d]) / (sum_n w[n,s] + 0.01)   (norm commutes out)
// Pipeline: memset ws acc -> prep (fold+bf16 weights) -> fused main -> finalize.
// ws layout (bytes):
//   [0,       524288) Wt   bf16 [1024][256]  rows 0..511 logits cols (h*64+s), 512..1023 fx cols
//   [524288,  526336) bc   f32  [512]
//   [526336,  788480) Tacc f32  [B*8*64*64]
//   [788480,  792576) norm f32  [B*8*64]

typedef __attribute__((ext_vector_type(8))) short short8;
typedef __attribute__((ext_vector_type(4))) short short4v;
typedef __attribute__((ext_vector_type(4))) float float4v;

#define WPITCH 264   // LDS row pitch (shorts) for 256-wide rows (+8 pad: banks spread)
#define TPITCH 72    // LDS row pitch (shorts) for 64-wide token rows (+8 pad)

__device__ __forceinline__ unsigned short f2bf(float f) {
    union { float f; unsigned int u; } v; v.f = f;
    unsigned int r = (v.u + 0x7FFFu + ((v.u >> 16) & 1u)) >> 16;  // RNE
    return (unsigned short)r;
}

// ---------------- prep: fold Wx@Wslice, convert to bf16 transposed ----------------
// grid 1024 blocks x 256 threads. Block j: output col j (0..511 logits, 512..1023 fx).
// Wt[j][c] layout: row j holds all 256 input-channel weights for output col j
// (B-operand wants K contiguous per output col).
__global__ void msfe_prep(const float* __restrict__ Wx, const float* __restrict__ bx,
                          const float* __restrict__ Wfx,
                          const float* __restrict__ Wslice, const float* __restrict__ bslice,
                          unsigned short* __restrict__ Wt, float* __restrict__ bc) {
    int j = blockIdx.x;
    int c = threadIdx.x;  // 0..255
    if (j < 512) {
        int h = j >> 6, s = j & 63;
        float acc = 0.f;
        #pragma unroll 8
        for (int d = 0; d < 64; ++d)
            acc += Wx[c * 512 + h * 64 + d] * Wslice[d * 64 + s];
        Wt[j * 256 + c] = f2bf(acc);
        if (c == 0) {
            float b = bslice[s];
            for (int d = 0; d < 64; ++d) b += bx[h * 64 + d] * Wslice[d * 64 + s];
            bc[j] = b;
        }
    } else {
        int col = j - 512;
        Wt[j * 256 + c] = f2bf(Wfx[c * 512 + col]);
    }
}

// ---------------- fused main ----------------
// 2048 blocks = 8 heads x 256 tiles (512 tokens each), 512 threads (8 waves), 1 block/CU.
// Block swizzle: the 8 head-blocks of one tile share an XCD in the same dispatch round
// (XCD = blockIdx%8 round-robin heuristic; perf-only, never correctness).
__global__ __launch_bounds__(512, 2)
void msfe_main(const float* __restrict__ x,
               const unsigned short* __restrict__ Wt,
               const float* __restrict__ bc,
               const float* __restrict__ bfx,
               const float* __restrict__ temperature,
               float* __restrict__ Tg, float* __restrict__ ng) {
    __shared__ unsigned short Ws[128 * WPITCH];  // head's weight slice: rows 0..63 logits, 64..127 fx
    __shared__ unsigned short Xs[64 * WPITCH];   // current 64-token x chunk (bf16)
    __shared__ unsigned short wT[64 * TPITCH];   // w transposed  [s][token]
    __shared__ unsigned short fT[64 * TPITCH];   // fx transposed [d][token]

    const int tid  = threadIdx.x;
    const int lane = tid & 63;
    const int wv   = tid >> 6;    // 0..7
    const int quad = lane >> 4;   // 0..3
    const int l16  = lane & 15;

    // blockIdx -> (round, xcd, tileInXcd, head): same tile's 8 heads => same xcd, same round
    const int bidx = blockIdx.x;
    const int c8   = bidx & 7;
    const int ti   = (bidx >> 3) & 3;
    const int head = (bidx >> 5) & 7;
    const int rnd  = bidx >> 8;
    const int tile = rnd * 32 + c8 * 4 + ti;      // 0..255
    const int batch = tile >> 7;                  // 0..1
    const long tok0 = (long)tile * 512;           // flat token base (B*N flat)

    // stage weight slice (64 KB) into LDS: row r<64 = logits col head*64+r, r>=64 = fx col
    {
        int r = tid & 127;
        int part = tid >> 7;  // 0..3, 64 shorts each
        int grow = (r < 64) ? (head * 64 + r) : (512 + head * 64 + (r - 64));
        const short4v* src = (const short4v*)(Wt + grow * 256 + part * 64);
        short4v* dst = (short4v*)(Ws + r * WPITCH + part * 64);
        #pragma unroll
        for (int j = 0; j < 16; ++j) dst[j] = src[j];
    }

    // stage x chunk 0: 64 tok x 256 ch fp32 -> bf16 LDS
    {
        const float4v* xg = (const float4v*)(x + tok0 * 256);
        #pragma unroll
        for (int i = 0; i < 8; ++i) {
            float4v v = xg[tid + i * 512];
            int f = (tid + i * 512) * 4;
            int trow = f >> 8, col = f & 255;
            short4v p;
            p.x = (short)f2bf(v.x); p.y = (short)f2bf(v.y);
            p.z = (short)f2bf(v.z); p.w = (short)f2bf(v.w);
            *(short4v*)(Xs + trow * WPITCH + col) = p;
        }
    }

    float bcr[4], bfxr[4];
    #pragma unroll
    for (int nt = 0; nt < 4; ++nt) {
        bcr[nt]  = bc [head * 64 + nt * 16 + l16];
        bfxr[nt] = bfx[head * 64 + nt * 16 + l16];
    }
    float tmp = temperature[head];
    tmp = fminf(fmaxf(tmp, 0.5f), 5.0f);
    const float invt = 1.0f / tmp;

    float4v Tac[2];
    Tac[0] = (float4v){0.f, 0.f, 0.f, 0.f};
    Tac[1] = (float4v){0.f, 0.f, 0.f, 0.f};
    float normAcc[4] = {0.f, 0.f, 0.f, 0.f};

    const int proj = wv >> 2;   // 0: logits+softmax waves, 1: fx waves
    const int tw   = wv & 3;    // token sub-tile (16 tokens)
    const int sh   = wv & 3;    // P3: s-tile
    const int dh   = wv >> 2;   // P3: d-half

    __syncthreads();

    for (int c = 0; c < 8; ++c) {
        // prefetch next x chunk into registers (overlaps with MFMA below)
        float4v xr[8];
        if (c < 7) {
            const float4v* xg = (const float4v*)(x + (tok0 + (long)(c + 1) * 64) * 256);
            #pragma unroll
            for (int i = 0; i < 8; ++i) xr[i] = xg[tid + i * 512];
        }

        // P1: projection MFMAs. wave computes 16 tokens x 64 cols of its proj. K=256.
        float4v acc[4];
        #pragma unroll
        for (int nt = 0; nt < 4; ++nt) acc[nt] = (float4v){0.f, 0.f, 0.f, 0.f};
        #pragma unroll
        for (int ks = 0; ks < 8; ++ks) {
            short8 a = *(const short8*)(Xs + (tw * 16 + l16) * WPITCH + ks * 32 + quad * 8);
            #pragma unroll
            for (int nt = 0; nt < 4; ++nt) {
                short8 b = *(const short8*)(Ws + (proj * 64 + nt * 16 + l16) * WPITCH + ks * 32 + quad * 8);
                acc[nt] = __builtin_amdgcn_mfma_f32_16x16x32_bf16(a, b, acc[nt], 0, 0, 0);
            }
        }

        // P2: epilogue. C layout: n(col)=l16+16*nt, m(row)=quad*4+r -> token=16*tw+quad*4+r
        if (proj == 0) {
            float v[4][4];
            #pragma unroll
            for (int nt = 0; nt < 4; ++nt)
                #pragma unroll
                for (int r = 0; r < 4; ++r)
                    v[nt][r] = (acc[nt][r] + bcr[nt]) * invt;
            #pragma unroll
            for (int r = 0; r < 4; ++r) {
                float m = fmaxf(fmaxf(v[0][r], v[1][r]), fmaxf(v[2][r], v[3][r]));
                m = fmaxf(m, __shfl_xor(m, 1));
                m = fmaxf(m, __shfl_xor(m, 2));
                m = fmaxf(m, __shfl_xor(m, 4));
                m = fmaxf(m, __shfl_xor(m, 8));
                float e0 = __expf(v[0][r] - m), e1 = __expf(v[1][r] - m);
                float e2 = __expf(v[2][r] - m), e3 = __expf(v[3][r] - m);
                float s = e0 + e1 + e2 + e3;
                s += __shfl_xor(s, 1); s += __shfl_xor(s, 2);
                s += __shfl_xor(s, 4); s += __shfl_xor(s, 8);
                float inv = 1.0f / s;
                v[0][r] = e0 * inv; v[1][r] = e1 * inv; v[2][r] = e2 * inv; v[3][r] = e3 * inv;
            }
            #pragma unroll
            for (int nt = 0; nt < 4; ++nt) {
                normAcc[nt] += v[nt][0] + v[nt][1] + v[nt][2] + v[nt][3];
                short4v p;
                p.x = (short)f2bf(v[nt][0]); p.y = (short)f2bf(v[nt][1]);
                p.z = (short)f2bf(v[nt][2]); p.w = (short)f2bf(v[nt][3]);
                // wT[s][token], 4 consecutive tokens packed
                *(short4v*)(wT + (nt * 16 + l16) * TPITCH + tw * 16 + quad * 4) = p;
            }
        } else {
            #pragma unroll
            for (int nt = 0; nt < 4; ++nt) {
                short4v p;
                p.x = (short)f2bf(acc[nt][0] + bfxr[nt]);
                p.y = (short)f2bf(acc[nt][1] + bfxr[nt]);
                p.z = (short)f2bf(acc[nt][2] + bfxr[nt]);
                p.w = (short)f2bf(acc[nt][3] + bfxr[nt]);
                *(short4v*)(fT + (nt * 16 + l16) * TPITCH + tw * 16 + quad * 4) = p;
            }
        }

        __syncthreads();

        // P3: T[s][d] += w^T fx over chunk tokens (K=64). wave: 16 s x 32 d.
        #pragma unroll
        for (int ks = 0; ks < 2; ++ks) {
            short8 a = *(const short8*)(wT + (sh * 16 + l16) * TPITCH + ks * 32 + quad * 8);
            #pragma unroll
            for (int nt = 0; nt < 2; ++nt) {
                short8 b = *(const short8*)(fT + (dh * 32 + nt * 16 + l16) * TPITCH + ks * 32 + quad * 8);
                Tac[nt] = __builtin_amdgcn_mfma_f32_16x16x32_bf16(a, b, Tac[nt], 0, 0, 0);
            }
        }

        // write next x chunk to LDS (X readers all passed the barrier above)
        if (c < 7) {
            #pragma unroll
            for (int i = 0; i < 8; ++i) {
                int f = tid * 4 + i * 2048;
                int trow = f >> 8, col = f & 255;
                short4v p;
                p.x = (short)f2bf(xr[i].x); p.y = (short)f2bf(xr[i].y);
                p.z = (short)f2bf(xr[i].z); p.w = (short)f2bf(xr[i].w);
                *(short4v*)(Xs + trow * WPITCH + col) = p;
            }
        }
        __syncthreads();
    }

    // epilogue: atomics into global accumulators
    const int basehs = (batch * 8 + head) * 64;
    #pragma unroll
    for (int nt = 0; nt < 2; ++nt) {
        #pragma unroll
        for (int r = 0; r < 4; ++r) {
            int s = sh * 16 + quad * 4 + r;
            int d = dh * 32 + nt * 16 + l16;
            atomicAdd(&Tg[(basehs + s) * 64 + d], Tac[nt][r]);
        }
    }
    if (wv < 4) {
        #pragma unroll
        for (int nt = 0; nt < 4; ++nt) {
            float v = normAcc[nt];
            v += __shfl_xor(v, 16);
            v += __shfl_xor(v, 32);
            if (quad == 0) atomicAdd(&ng[basehs + nt * 16 + l16], v);
        }
    }
}

// ---------------- finalize ----------------
__global__ void msfe_final(const float* __restrict__ Tg, const float* __restrict__ ng,
                           float* __restrict__ out) {
    int i = blockIdx.x * 256 + threadIdx.x;  // 65536
    out[i] = Tg[i] / (ng[i >> 6] + 0.01f);
}

extern "C" void kernel_launch(void* const* d_in, const int* in_sizes, int n_in,
                              void* d_out, int out_size, void* d_ws, size_t ws_size,
                              hipStream_t stream) {
    const float* x       = (const float*)d_in[0];
    const float* Wx      = (const float*)d_in[1];
    const float* bx      = (const float*)d_in[2];
    const float* Wfx     = (const float*)d_in[3];
    const float* bfx     = (const float*)d_in[4];
    const float* Wslice  = (const float*)d_in[5];
    const float* bslice  = (const float*)d_in[6];
    const float* temp    = (const float*)d_in[7];

    char* ws = (char*)d_ws;
    unsigned short* Wt = (unsigned short*)ws;       // 524288 B
    float* bc = (float*)(ws + 524288);              // 2048 B
    float* Tg = (float*)(ws + 526336);              // 262144 B
    float* ng = (float*)(ws + 788480);              // 4096 B

    // zero accumulators (ws is poisoned 0xAA before every timed launch)
    hipMemsetAsync(Tg, 0, 262144 + 4096, stream);

    msfe_prep<<<1024, 256, 0, stream>>>(Wx, bx, Wfx, Wslice, bslice, Wt, bc);
    msfe_main<<<2048, 512, 0, stream>>>(x, Wt, bc, bfx, temp, Tg, ng);
    msfe_final<<<256, 256, 0, stream>>>(Tg, ng, (float*)d_out);
}